// Round 13
// baseline (589.864 us; speedup 1.0000x reference)
//
#include <hip/hip_runtime.h>
#include <hip/hip_bf16.h>

#define NN 100000     // nodes
#define NE 1600000    // edges before self loops
#define ET 1700000    // NE + NN
#define CH 128        // hidden channels (H*C, H=1)

typedef unsigned int u32;
typedef unsigned short u16;

typedef __attribute__((ext_vector_type(8))) short bf16x8;
typedef __attribute__((ext_vector_type(4))) float f32x4;
typedef __attribute__((ext_vector_type(2))) float f32x2;

__device__ __forceinline__ float lo2f(u32 w) { return __uint_as_float(w << 16); }
__device__ __forceinline__ float hi2f(u32 w) { return __uint_as_float(w & 0xFFFF0000u); }
__device__ __forceinline__ u32 f2bits(float v) {
    __hip_bfloat16 t = __float2bfloat16(v);
    return (u32)*(u16*)&t;
}
__device__ __forceinline__ u32 pack2(float a, float b) {
    return (f2bits(b) << 16) | f2bits(a);
}
// fp8 e4m3 HW converts — word-select must be a compile-time constant
template<bool HI>
__device__ __forceinline__ int pk_fp8(float a, float b, int old) {
    return __builtin_amdgcn_cvt_pk_fp8_f32(a, b, old, HI);
}
template<bool HI>
__device__ __forceinline__ f32x2 unpk_fp8(u32 w) {
    return __builtin_amdgcn_cvt_pk_f32_fp8((int)w, HI);
}

// ---------------------------------------------------------------------------
// CSR build: cnt[dst]++ -> 2-level exclusive scan -> scatter
// ---------------------------------------------------------------------------
__global__ __launch_bounds__(256) void k_deg(
    const int* __restrict__ ei, u32* __restrict__ cnt)
{
    int e = blockIdx.x * 256 + threadIdx.x;
    if (e >= ET) return;
    int d = (e < NE) ? ei[NE + e] : e - NE;
    if ((u32)d >= NN) d = 0;
    atomicAdd(&cnt[d], 1u);
}

__global__ __launch_bounds__(256) void k_scanA(
    const u32* __restrict__ cnt, u32* __restrict__ bsum)
{
    __shared__ u32 s[256];
    int i = blockIdx.x * 256 + threadIdx.x;
    s[threadIdx.x] = (i < NN) ? cnt[i] : 0u;
    __syncthreads();
    for (int off = 128; off; off >>= 1) {
        if (threadIdx.x < off) s[threadIdx.x] += s[threadIdx.x + off];
        __syncthreads();
    }
    if (threadIdx.x == 0) bsum[blockIdx.x] = s[0];
}

__global__ __launch_bounds__(512) void k_scanB(u32* __restrict__ bsum, int nb)
{
    __shared__ u32 s[512];
    int t = threadIdx.x;
    u32 v = (t < nb) ? bsum[t] : 0u;
    s[t] = v; __syncthreads();
    for (int off = 1; off < 512; off <<= 1) {
        u32 a = (t >= off) ? s[t - off] : 0u;
        __syncthreads();
        s[t] += a;
        __syncthreads();
    }
    if (t < nb) bsum[t] = s[t] - v;    // exclusive block offsets
}

// scanC also zeroes cnt (saves the second memset launch)
__global__ __launch_bounds__(256) void k_scanC(
    u32* __restrict__ cnt, const u32* __restrict__ bsum,
    u32* __restrict__ rowptr)
{
    __shared__ u32 s[256];
    int i = blockIdx.x * 256 + threadIdx.x;
    u32 v = (i < NN) ? cnt[i] : 0u;
    if (i < NN) cnt[i] = 0u;
    s[threadIdx.x] = v; __syncthreads();
    for (int off = 1; off < 256; off <<= 1) {
        u32 a = (threadIdx.x >= off) ? s[threadIdx.x - off] : 0u;
        __syncthreads();
        s[threadIdx.x] += a;
        __syncthreads();
    }
    if (i < NN) rowptr[i] = s[threadIdx.x] - v + bsum[blockIdx.x];
    if (i == 0) rowptr[NN] = ET;
}

// scatter one 16B edge record {src, ew(bf16x2), eid, (ex later)} + out_idx
__global__ __launch_bounds__(256) void k_scatter(
    const int* __restrict__ ei, const float* __restrict__ ew,
    const u32* __restrict__ rowptr, u32* __restrict__ cnt,
    uint4* __restrict__ erec, float* __restrict__ out_idx)
{
    int e = blockIdx.x * 256 + threadIdx.x;
    if (e >= ET) return;
    int s, d; float w0, w1;
    if (e < NE) {
        s = ei[e]; d = ei[NE + e];
        w0 = ew[2 * e]; w1 = ew[2 * e + 1];
    } else {
        s = d = e - NE; w0 = 0.f; w1 = 0.f;
    }
    out_idx[e]      = (float)s;
    out_idx[ET + e] = (float)d;
    if ((u32)d >= NN) d = 0;
    if ((u32)s >= NN) s = 0;
    u32 pos = rowptr[d] + atomicAdd(&cnt[d], 1u);
    erec[pos] = make_uint4((u32)s, pack2(w0, w1), (u32)e, 0u);
}

// ---------------------------------------------------------------------------
// k_pre: xl = x@Wl+bl -> fp8 (128 B/row); xr = x@Wr+br -> bf16 (256 B/row)
// Thread = (n, 4 channels).
// ---------------------------------------------------------------------------
__global__ __launch_bounds__(256) void k_pre(
    const float* __restrict__ x,
    const float* __restrict__ Wl, const float* __restrict__ bl,
    const float* __restrict__ Wr, const float* __restrict__ br,
    u32* __restrict__ xl8, uint2* __restrict__ xrh)
{
    __shared__ float sWl[6][CH], sWr[6][CH], sbl[CH], sbr[CH];
    for (int i = threadIdx.x; i < 6 * CH; i += 256) {
        sWl[i / CH][i % CH] = Wl[i];
        sWr[i / CH][i % CH] = Wr[i];
    }
    for (int i = threadIdx.x; i < CH; i += 256) { sbl[i] = bl[i]; sbr[i] = br[i]; }
    __syncthreads();

    int tid = blockIdx.x * 256 + threadIdx.x;   // grid covers NN*32 exactly
    int n = tid >> 5, q = tid & 31, c0 = q * 4;
    float xs[6];
#pragma unroll
    for (int k = 0; k < 6; ++k) xs[k] = x[n * 6 + k];
    float l[4], r[4];
#pragma unroll
    for (int j = 0; j < 4; ++j) { l[j] = sbl[c0 + j]; r[j] = sbr[c0 + j]; }
#pragma unroll
    for (int k = 0; k < 6; ++k)
#pragma unroll
        for (int j = 0; j < 4; ++j) {
            l[j] += xs[k] * sWl[k][c0 + j];
            r[j] += xs[k] * sWr[k][c0 + j];
        }
    int v = pk_fp8<false>(l[0], l[1], 0);
    v = pk_fp8<true>(l[2], l[3], v);
    xl8[tid] = (u32)v;                               // bytes = channels c0..c0+3
    xrh[tid] = make_uint2(pack2(r[0], r[1]), pack2(r[2], r[3]));
}

// ---------------------------------------------------------------------------
// k_fused (wave/node; 8 edge-groups of 8 lanes x 16 channels):
//   per edge: z = xl[src] + xr[n] + ea@We; s = att.leaky(z) (3-step butterfly)
//   ex = exp(s) -> erec[p].w;  den += ex; num += ex*xl
//   h[n] = relu(num/den + b_gat) -> bf16 row written OVER xr slot n (race-free)
//   8 independent 16B gathers in flight per wave iteration.
// ---------------------------------------------------------------------------
__global__ __launch_bounds__(256) void k_fused(
    const u32* __restrict__ rowptr, uint4* erec,
    const u32* __restrict__ xl8,
    const float* __restrict__ We, const float* __restrict__ att,
    const float* __restrict__ bgat,
    uint4* xr,                        // in: xr bf16 ; out: h bf16 (in place)
    float* __restrict__ den_g)
{
    int n = (blockIdx.x << 2) + (threadIdx.x >> 6);   // grid: NN/4
    int lane = threadIdx.x & 63;
    int g = lane >> 3;            // edge-group 0..7
    int gl = lane & 7;            // lane in group
    int c0 = gl * 16;             // 16 channels per lane

    float we0[16], we1[16], at[16];
#pragma unroll
    for (int j = 0; j < 16; ++j) {
        we0[j] = We[c0 + j];
        we1[j] = We[CH + c0 + j];
        at[j]  = att[c0 + j];
    }

    const uint4* xrp = xr + (size_t)n * 16;
    uint4 xa = xrp[2 * gl], xb = xrp[2 * gl + 1];
    float xrv[16] = {lo2f(xa.x), hi2f(xa.x), lo2f(xa.y), hi2f(xa.y),
                     lo2f(xa.z), hi2f(xa.z), lo2f(xa.w), hi2f(xa.w),
                     lo2f(xb.x), hi2f(xb.x), lo2f(xb.y), hi2f(xb.y),
                     lo2f(xb.z), hi2f(xb.z), lo2f(xb.w), hi2f(xb.w)};

    u32 p0 = rowptr[n], p1 = rowptr[n + 1];
    float den = 0.f;
    float num[16];
#pragma unroll
    for (int j = 0; j < 16; ++j) num[j] = 0.f;

    for (u32 p = p0 + g; p < p1; p += 8) {
        uint4 er = erec[p];                      // coalesced across groups
        float ea0 = lo2f(er.y), ea1 = hi2f(er.y);
        uint4 w = ((const uint4*)xl8)[(size_t)er.x * 8 + gl];  // 16 fp8 chans
        f32x2 d0 = unpk_fp8<false>(w.x), d1 = unpk_fp8<true>(w.x);
        f32x2 d2 = unpk_fp8<false>(w.y), d3 = unpk_fp8<true>(w.y);
        f32x2 d4 = unpk_fp8<false>(w.z), d5 = unpk_fp8<true>(w.z);
        f32x2 d6 = unpk_fp8<false>(w.w), d7 = unpk_fp8<true>(w.w);
        float xl[16] = {d0.x, d0.y, d1.x, d1.y, d2.x, d2.y, d3.x, d3.y,
                        d4.x, d4.y, d5.x, d5.y, d6.x, d6.y, d7.x, d7.y};
        float s = 0.f;
#pragma unroll
        for (int j = 0; j < 16; ++j) {
            float z = xl[j] + xrv[j] + ea0 * we0[j] + ea1 * we1[j];
            z = z > 0.f ? z : 0.2f * z;         // leaky_relu(0.2)
            s += z * at[j];
        }
        s += __shfl_xor(s, 1, 64);
        s += __shfl_xor(s, 2, 64);
        s += __shfl_xor(s, 4, 64);              // all 8 lanes hold s
        s = fminf(fmaxf(s, -60.f), 60.f);
        float ex = __expf(s);
        den += ex;
#pragma unroll
        for (int j = 0; j < 16; ++j) num[j] += ex * xl[j];
        if (gl == 0) erec[p].w = __float_as_uint(ex);
    }
    // cross-group merge (8 groups)
    den += __shfl_xor(den, 8, 64);
    den += __shfl_xor(den, 16, 64);
    den += __shfl_xor(den, 32, 64);
#pragma unroll
    for (int j = 0; j < 16; ++j) {
        num[j] += __shfl_xor(num[j], 8, 64);
        num[j] += __shfl_xor(num[j], 16, 64);
        num[j] += __shfl_xor(num[j], 32, 64);
    }
    float rden = (den > 1e-30f) ? 1.f / den : 0.f;
    if (lane == 0) den_g[n] = den;
    if (g == 0) {
        float r[16];
#pragma unroll
        for (int j = 0; j < 16; ++j) {
            float v = num[j] * rden + bgat[c0 + j];
            r[j] = v > 0.f ? v : 0.f;
        }
        uint4* hrow = xr + (size_t)n * 16;
        hrow[2 * gl]     = make_uint4(pack2(r[0], r[1]), pack2(r[2], r[3]),
                                      pack2(r[4], r[5]), pack2(r[6], r[7]));
        hrow[2 * gl + 1] = make_uint4(pack2(r[8], r[9]), pack2(r[10], r[11]),
                                      pack2(r[12], r[13]), pack2(r[14], r[15]));
    }
}

// ---------------------------------------------------------------------------
// GEMM1 (MFMA): hg = h @ W2; h bf16 rows (256 B), hg -> fp8 rows (128 B).
//   hg8 slot s (uint2, 8 B) of row n holds channels {16j+s, j=0..7}.
//   Fragment layouts (HW-verified m89/m91/m120):
//     A[m=lane&15][k=quad*8+j], B[k=quad*8+j][n=lane&15], D col=lane&15,
//     row=quad*4+reg.
// ---------------------------------------------------------------------------
__global__ __launch_bounds__(256) void k_gemm1(
    const u32* __restrict__ hb, const float* __restrict__ W2,
    uint2* __restrict__ hg8)
{
    int lane = threadIdx.x & 63;
    int wv = threadIdx.x >> 6;
    int quad = lane >> 4;
    int l15 = lane & 15;

    // B fragments [kc][n0], once per block (W2 is L2-hot)
    bf16x8 bfrag[4][8];
#pragma unroll
    for (int kc = 0; kc < 4; ++kc) {
#pragma unroll
        for (int n0 = 0; n0 < 8; ++n0) {
            int kbase = kc * 32 + quad * 8;
            int col = n0 * 16 + l15;
            union { bf16x8 v; u32 u[4]; } t;
#pragma unroll
            for (int jj = 0; jj < 4; ++jj) {
                float w0 = W2[(kbase + 2 * jj) * CH + col];
                float w1 = W2[(kbase + 2 * jj + 1) * CH + col];
                t.u[jj] = pack2(w0, w1);
            }
            bfrag[kc][n0] = t.v;
        }
    }

    const int nchunk = (NN + 63) / 64;       // 1563
    for (int ch = blockIdx.x; ch < nchunk; ch += gridDim.x) {
        int m0 = ch * 64 + wv * 16;
        int arow = m0 + l15;
        if (arow >= NN) arow = NN - 1;       // clamp (stores guarded)
        const uint4* ap = (const uint4*)(hb + (size_t)arow * 64);

        bf16x8 afrag[4];
#pragma unroll
        for (int kc = 0; kc < 4; ++kc) {
            union { uint4 q; bf16x8 v; } t;
            t.q = ap[kc * 4 + quad];
            afrag[kc] = t.v;
        }

        f32x4 acc[8];
#pragma unroll
        for (int n0 = 0; n0 < 8; ++n0) acc[n0] = (f32x4){0.f, 0.f, 0.f, 0.f};
#pragma unroll
        for (int n0 = 0; n0 < 8; ++n0)
#pragma unroll
            for (int kc = 0; kc < 4; ++kc)
                acc[n0] = __builtin_amdgcn_mfma_f32_16x16x32_bf16(
                    afrag[kc], bfrag[kc][n0], acc[n0], 0, 0, 0);

#pragma unroll
        for (int r = 0; r < 4; ++r) {
            int row = m0 + quad * 4 + r;
            if (row < NN) {
                int a = pk_fp8<false>(acc[0][r], acc[1][r], 0);
                a = pk_fp8<true>(acc[2][r], acc[3][r], a);
                int b = pk_fp8<false>(acc[4][r], acc[5][r], 0);
                b = pk_fp8<true>(acc[6][r], acc[7][r], b);
                hg8[(size_t)row * 16 + l15] = make_uint2((u32)a, (u32)b);
            }
        }
    }
}

// ---------------------------------------------------------------------------
// k_h2f (wave/node; 8 edge-groups of 8 lanes x 16 channels):
//   one 16B erec load/edge: {src, -, eid, ex}; alpha = ex/den_g[n];
//   out_alpha[eid] = alpha; h2 += alpha * hg8[src] (fp8, slots 2gl & 2gl+1);
//   out[n,:] = relu(h2+b_gcn)@W3 + b3.  (norm == alpha: deg == 1 identity)
//   acc[0..7] = channels 16j+2gl; acc[8..15] = channels 16j+2gl+1.
// ---------------------------------------------------------------------------
__global__ __launch_bounds__(256) void k_h2f(
    const u32* __restrict__ rowptr, const uint4* __restrict__ erec,
    const float* __restrict__ den_g, const uint2* __restrict__ hg8,
    const float* __restrict__ bgcn, const float* __restrict__ W3,
    const float* __restrict__ b3,
    float* __restrict__ out_alpha, float* __restrict__ out)
{
    int n = (blockIdx.x << 2) + (threadIdx.x >> 6);
    int lane = threadIdx.x & 63;
    int g = lane >> 3;
    int gl = lane & 7;

    float w30[16], w31[16], bg[16];
#pragma unroll
    for (int j = 0; j < 8; ++j) {
        int ca = 16 * j + 2 * gl;
        int cb = ca + 1;
        w30[j]     = W3[2 * ca]; w31[j]     = W3[2 * ca + 1]; bg[j]     = bgcn[ca];
        w30[j + 8] = W3[2 * cb]; w31[j + 8] = W3[2 * cb + 1]; bg[j + 8] = bgcn[cb];
    }

    float dn = den_g[n];
    float rden = (dn > 1e-30f) ? 1.f / dn : 0.f;
    u32 p0 = rowptr[n], p1 = rowptr[n + 1];
    float acc[16];
#pragma unroll
    for (int j = 0; j < 16; ++j) acc[j] = 0.f;

    for (u32 p = p0 + g; p < p1; p += 8) {
        uint4 er = erec[p];
        float a = __uint_as_float(er.w) * rden;
        if (gl == 0) out_alpha[er.z] = a;
        uint4 w = ((const uint4*)hg8)[(size_t)er.x * 8 + gl];  // slots 2gl,2gl+1
        f32x2 d0 = unpk_fp8<false>(w.x), d1 = unpk_fp8<true>(w.x);
        f32x2 d2 = unpk_fp8<false>(w.y), d3 = unpk_fp8<true>(w.y);
        f32x2 d4 = unpk_fp8<false>(w.z), d5 = unpk_fp8<true>(w.z);
        f32x2 d6 = unpk_fp8<false>(w.w), d7 = unpk_fp8<true>(w.w);
        acc[0]  += a * d0.x; acc[1]  += a * d0.y;
        acc[2]  += a * d1.x; acc[3]  += a * d1.y;
        acc[4]  += a * d2.x; acc[5]  += a * d2.y;
        acc[6]  += a * d3.x; acc[7]  += a * d3.y;
        acc[8]  += a * d4.x; acc[9]  += a * d4.y;
        acc[10] += a * d5.x; acc[11] += a * d5.y;
        acc[12] += a * d6.x; acc[13] += a * d6.y;
        acc[14] += a * d7.x; acc[15] += a * d7.y;
    }
#pragma unroll
    for (int j = 0; j < 16; ++j) {
        acc[j] += __shfl_xor(acc[j], 8, 64);
        acc[j] += __shfl_xor(acc[j], 16, 64);
        acc[j] += __shfl_xor(acc[j], 32, 64);
    }
    float o0 = 0.f, o1 = 0.f;
#pragma unroll
    for (int j = 0; j < 16; ++j) {
        float v = acc[j] + bg[j];
        v = v > 0.f ? v : 0.f;
        o0 += v * w30[j];
        o1 += v * w31[j];
    }
    o0 += __shfl_xor(o0, 1, 64); o1 += __shfl_xor(o1, 1, 64);
    o0 += __shfl_xor(o0, 2, 64); o1 += __shfl_xor(o1, 2, 64);
    o0 += __shfl_xor(o0, 4, 64); o1 += __shfl_xor(o1, 4, 64);
    if (lane == 0) {
        out[n * 2]     = o0 + b3[0];
        out[n * 2 + 1] = o1 + b3[1];
    }
}

// ---------------------------------------------------------------------------
extern "C" void kernel_launch(void* const* d_in, const int* in_sizes, int n_in,
                              void* d_out, int out_size, void* d_ws, size_t ws_size,
                              hipStream_t stream)
{
    const float* x    = (const float*)d_in[0];
    const int*   ei   = (const int*)d_in[1];
    const float* ew   = (const float*)d_in[2];
    const float* Wl   = (const float*)d_in[3];
    const float* bl   = (const float*)d_in[4];
    const float* Wr   = (const float*)d_in[5];
    const float* br   = (const float*)d_in[6];
    const float* We   = (const float*)d_in[7];
    const float* att  = (const float*)d_in[8];
    const float* bgat = (const float*)d_in[9];
    const float* W2   = (const float*)d_in[10];
    const float* bgcn = (const float*)d_in[11];
    const float* W3   = (const float*)d_in[12];
    const float* b3   = (const float*)d_in[13];

    float* out       = (float*)d_out;          // chunk0: out [N,2] f32
    float* out_idx   = out + 200000;           // chunk1: stack([src,dst]) [2,ET]
    float* out_alpha = out + 200000 + 2 * ET;  // chunk2: alpha [ET,1]

    // workspace (~66.5 MB):
    // xl8 u32[NN*32] (fp8 xl; later hg8 fp8)  | xrh uint2[NN*32] (bf16 xr -> h)
    // | erec uint4[ET] | cnt u32[NN] (later den_g f32) | rowptr[NN+1] | bsum[512]
    u32*   xl8    = (u32*)d_ws;
    uint2* xrh    = (uint2*)(xl8 + (size_t)NN * 32);
    uint4* erec   = (uint4*)(xrh + (size_t)NN * 32);
    u32*   cnt    = (u32*)(erec + ET);
    float* den    = (float*)cnt;               // aliased after scatter
    u32*   rowptr = cnt + NN;
    u32*   bsum   = rowptr + NN + 1;

    const int EB = (ET + 255) / 256;
    const int SB = (NN + 255) / 256;           // 391

    // --- CSR build (+ out_idx) ---
    hipMemsetAsync(cnt, 0, NN * sizeof(u32), stream);
    k_deg<<<EB, 256, 0, stream>>>(ei, cnt);
    k_scanA<<<SB, 256, 0, stream>>>(cnt, bsum);
    k_scanB<<<1, 512, 0, stream>>>(bsum, SB);
    k_scanC<<<SB, 256, 0, stream>>>(cnt, bsum, rowptr);   // also zeroes cnt
    k_scatter<<<EB, 256, 0, stream>>>(ei, ew, rowptr, cnt, erec, out_idx);

    // --- projections + fused attention/aggregation ---
    k_pre<<<(NN * 32) / 256, 256, 0, stream>>>(x, Wl, bl, Wr, br, xl8, xrh);
    k_fused<<<NN / 4, 256, 0, stream>>>(rowptr, erec, xl8, We, att, bgat,
                                        (uint4*)xrh, den);

    // --- GCN (MFMA, fp8 out) + fused h2+MLP ---
    k_gemm1<<<512, 256, 0, stream>>>((const u32*)xrh, W2, (uint2*)xl8);
    k_h2f<<<NN / 4, 256, 0, stream>>>(rowptr, erec, den, (const uint2*)xl8,
                                      bgcn, W3, b3, out_alpha, out);
}

// Round 14
// 490.250 us; speedup vs baseline: 1.2032x; 1.2032x over previous
//
#include <hip/hip_runtime.h>
#include <hip/hip_bf16.h>

#define NN 100000     // nodes
#define NE 1600000    // edges before self loops
#define ET 1700000    // NE + NN
#define CH 128        // hidden channels (H*C, H=1)

typedef unsigned int u32;
typedef unsigned short u16;

typedef __attribute__((ext_vector_type(8))) short bf16x8;
typedef __attribute__((ext_vector_type(4))) float f32x4;
typedef __attribute__((ext_vector_type(2))) float f32x2;

__device__ __forceinline__ float lo2f(u32 w) { return __uint_as_float(w << 16); }
__device__ __forceinline__ float hi2f(u32 w) { return __uint_as_float(w & 0xFFFF0000u); }
__device__ __forceinline__ u32 f2bits(float v) {
    __hip_bfloat16 t = __float2bfloat16(v);
    return (u32)*(u16*)&t;
}
__device__ __forceinline__ u32 pack2(float a, float b) {
    return (f2bits(b) << 16) | f2bits(a);
}
// fp8 e4m3 HW converts — word-select must be a compile-time constant
template<bool HI>
__device__ __forceinline__ int pk_fp8(float a, float b, int old) {
    return __builtin_amdgcn_cvt_pk_fp8_f32(a, b, old, HI);
}
template<bool HI>
__device__ __forceinline__ f32x2 unpk_fp8(u32 w) {
    return __builtin_amdgcn_cvt_pk_f32_fp8((int)w, HI);
}

// ---------------------------------------------------------------------------
// CSR build: cnt[dst]++ -> 2-level exclusive scan -> scatter
// ---------------------------------------------------------------------------
__global__ __launch_bounds__(256) void k_deg(
    const int* __restrict__ ei, u32* __restrict__ cnt)
{
    int e = blockIdx.x * 256 + threadIdx.x;
    if (e >= ET) return;
    int d = (e < NE) ? ei[NE + e] : e - NE;
    if ((u32)d >= NN) d = 0;
    atomicAdd(&cnt[d], 1u);
}

__global__ __launch_bounds__(256) void k_scanA(
    const u32* __restrict__ cnt, u32* __restrict__ bsum)
{
    __shared__ u32 s[256];
    int i = blockIdx.x * 256 + threadIdx.x;
    s[threadIdx.x] = (i < NN) ? cnt[i] : 0u;
    __syncthreads();
    for (int off = 128; off; off >>= 1) {
        if (threadIdx.x < off) s[threadIdx.x] += s[threadIdx.x + off];
        __syncthreads();
    }
    if (threadIdx.x == 0) bsum[blockIdx.x] = s[0];
}

__global__ __launch_bounds__(512) void k_scanB(u32* __restrict__ bsum, int nb)
{
    __shared__ u32 s[512];
    int t = threadIdx.x;
    u32 v = (t < nb) ? bsum[t] : 0u;
    s[t] = v; __syncthreads();
    for (int off = 1; off < 512; off <<= 1) {
        u32 a = (t >= off) ? s[t - off] : 0u;
        __syncthreads();
        s[t] += a;
        __syncthreads();
    }
    if (t < nb) bsum[t] = s[t] - v;    // exclusive block offsets
}

// scanC also zeroes cnt (saves the second memset launch)
__global__ __launch_bounds__(256) void k_scanC(
    u32* __restrict__ cnt, const u32* __restrict__ bsum,
    u32* __restrict__ rowptr)
{
    __shared__ u32 s[256];
    int i = blockIdx.x * 256 + threadIdx.x;
    u32 v = (i < NN) ? cnt[i] : 0u;
    if (i < NN) cnt[i] = 0u;
    s[threadIdx.x] = v; __syncthreads();
    for (int off = 1; off < 256; off <<= 1) {
        u32 a = (threadIdx.x >= off) ? s[threadIdx.x - off] : 0u;
        __syncthreads();
        s[threadIdx.x] += a;
        __syncthreads();
    }
    if (i < NN) rowptr[i] = s[threadIdx.x] - v + bsum[blockIdx.x];
    if (i == 0) rowptr[NN] = ET;
}

// scatter one 16B edge record {src, ew(bf16x2), eid, (ex later)} + out_idx
__global__ __launch_bounds__(256) void k_scatter(
    const int* __restrict__ ei, const float* __restrict__ ew,
    const u32* __restrict__ rowptr, u32* __restrict__ cnt,
    uint4* __restrict__ erec, float* __restrict__ out_idx)
{
    int e = blockIdx.x * 256 + threadIdx.x;
    if (e >= ET) return;
    int s, d; float w0, w1;
    if (e < NE) {
        s = ei[e]; d = ei[NE + e];
        w0 = ew[2 * e]; w1 = ew[2 * e + 1];
    } else {
        s = d = e - NE; w0 = 0.f; w1 = 0.f;
    }
    out_idx[e]      = (float)s;
    out_idx[ET + e] = (float)d;
    if ((u32)d >= NN) d = 0;
    if ((u32)s >= NN) s = 0;
    u32 pos = rowptr[d] + atomicAdd(&cnt[d], 1u);
    erec[pos] = make_uint4((u32)s, pack2(w0, w1), (u32)e, 0u);
}

// ---------------------------------------------------------------------------
// k_pre: xl = x@Wl+bl -> fp8 (128 B/row); xr = x@Wr+br -> bf16 (256 B/row)
// Thread = (n, 4 channels).
// ---------------------------------------------------------------------------
__global__ __launch_bounds__(256) void k_pre(
    const float* __restrict__ x,
    const float* __restrict__ Wl, const float* __restrict__ bl,
    const float* __restrict__ Wr, const float* __restrict__ br,
    u32* __restrict__ xl8, uint2* __restrict__ xrh)
{
    __shared__ float sWl[6][CH], sWr[6][CH], sbl[CH], sbr[CH];
    for (int i = threadIdx.x; i < 6 * CH; i += 256) {
        sWl[i / CH][i % CH] = Wl[i];
        sWr[i / CH][i % CH] = Wr[i];
    }
    for (int i = threadIdx.x; i < CH; i += 256) { sbl[i] = bl[i]; sbr[i] = br[i]; }
    __syncthreads();

    int tid = blockIdx.x * 256 + threadIdx.x;   // grid covers NN*32 exactly
    int n = tid >> 5, q = tid & 31, c0 = q * 4;
    float xs[6];
#pragma unroll
    for (int k = 0; k < 6; ++k) xs[k] = x[n * 6 + k];
    float l[4], r[4];
#pragma unroll
    for (int j = 0; j < 4; ++j) { l[j] = sbl[c0 + j]; r[j] = sbr[c0 + j]; }
#pragma unroll
    for (int k = 0; k < 6; ++k)
#pragma unroll
        for (int j = 0; j < 4; ++j) {
            l[j] += xs[k] * sWl[k][c0 + j];
            r[j] += xs[k] * sWr[k][c0 + j];
        }
    int v = pk_fp8<false>(l[0], l[1], 0);
    v = pk_fp8<true>(l[2], l[3], v);
    xl8[tid] = (u32)v;                               // bytes = channels c0..c0+3
    xrh[tid] = make_uint2(pack2(r[0], r[1]), pack2(r[2], r[3]));
}

// ---------------------------------------------------------------------------
// k_fused (wave/node; 4 edge-groups of 16 lanes x 8 channels) with a depth-2
// software pipeline: erec fetched 2 iters ahead, xl8 gather issued 1 iter
// ahead — the gather latency overlaps a full compute stage.
//   per edge: z = xl[src] + xr[n] + ea@We; s = att.leaky(z) (4-step butterfly)
//   ex = exp(s) -> erec[p].w;  den += ex; num += ex*xl
//   h[n] = relu(num/den + b_gat) -> bf16 row over xr slot n (race-free).
// ---------------------------------------------------------------------------
__global__ __launch_bounds__(256) void k_fused(
    const u32* __restrict__ rowptr, uint4* erec,
    const u32* __restrict__ xl8,
    const float* __restrict__ We, const float* __restrict__ att,
    const float* __restrict__ bgat,
    uint4* xr,                        // in: xr bf16 ; out: h bf16 (in place)
    float* __restrict__ den_g)
{
    int n = (blockIdx.x << 2) + (threadIdx.x >> 6);   // grid: NN/4
    int lane = threadIdx.x & 63;
    int g = lane >> 4;            // edge-group 0..3
    int gl = lane & 15;           // lane in group
    int c0 = gl * 8;              // 8 channels per lane

    float we0[8], we1[8], at[8];
#pragma unroll
    for (int j = 0; j < 8; ++j) {
        we0[j] = We[c0 + j];
        we1[j] = We[CH + c0 + j];
        at[j]  = att[c0 + j];
    }

    uint4 xw = xr[(size_t)n * 16 + gl];   // 8 bf16 channels
    float xrv[8] = {lo2f(xw.x), hi2f(xw.x), lo2f(xw.y), hi2f(xw.y),
                    lo2f(xw.z), hi2f(xw.z), lo2f(xw.w), hi2f(xw.w)};

    u32 p0 = rowptr[n], p1 = rowptr[n + 1];
    u32 last = p1 - 1;                    // >= p0 (self-loop guarantees >=1)
    float den = 0.f;
    float num[8] = {0.f, 0.f, 0.f, 0.f, 0.f, 0.f, 0.f, 0.f};

    u32 p = p0 + g;
    uint4 er0 = erec[p <= last ? p : last];
    uint4 er1 = erec[p + 4 <= last ? p + 4 : last];
    uint2 w0 = ((const uint2*)xl8)[(size_t)er0.x * 16 + gl];

    for (; p < p1; p += 4) {
        uint4 er2 = erec[p + 8 <= last ? p + 8 : last];             // prefetch
        uint2 w1 = ((const uint2*)xl8)[(size_t)er1.x * 16 + gl];    // prefetch
        float ea0 = lo2f(er0.y), ea1 = hi2f(er0.y);
        f32x2 d0 = unpk_fp8<false>(w0.x), d1 = unpk_fp8<true>(w0.x);
        f32x2 d2 = unpk_fp8<false>(w0.y), d3 = unpk_fp8<true>(w0.y);
        float xl[8] = {d0.x, d0.y, d1.x, d1.y, d2.x, d2.y, d3.x, d3.y};
        float s = 0.f;
#pragma unroll
        for (int j = 0; j < 8; ++j) {
            float z = xl[j] + xrv[j] + ea0 * we0[j] + ea1 * we1[j];
            z = z > 0.f ? z : 0.2f * z;         // leaky_relu(0.2)
            s += z * at[j];
        }
        s += __shfl_xor(s, 1, 64);
        s += __shfl_xor(s, 2, 64);
        s += __shfl_xor(s, 4, 64);
        s += __shfl_xor(s, 8, 64);              // all 16 lanes hold s
        s = fminf(fmaxf(s, -60.f), 60.f);
        float ex = __expf(s);
        den += ex;
#pragma unroll
        for (int j = 0; j < 8; ++j) num[j] += ex * xl[j];
        if (gl == 0) erec[p].w = __float_as_uint(ex);
        er0 = er1; er1 = er2; w0 = w1;
    }
    // cross-group merge
    den += __shfl_xor(den, 16, 64);
    den += __shfl_xor(den, 32, 64);
#pragma unroll
    for (int j = 0; j < 8; ++j) {
        num[j] += __shfl_xor(num[j], 16, 64);
        num[j] += __shfl_xor(num[j], 32, 64);
    }
    float rden = (den > 1e-30f) ? 1.f / den : 0.f;
    if (lane == 0) den_g[n] = den;
    if (g == 0) {
        float r[8];
#pragma unroll
        for (int j = 0; j < 8; ++j) {
            float v = num[j] * rden + bgat[c0 + j];
            r[j] = v > 0.f ? v : 0.f;
        }
        xr[(size_t)n * 16 + gl] = make_uint4(pack2(r[0], r[1]), pack2(r[2], r[3]),
                                             pack2(r[4], r[5]), pack2(r[6], r[7]));
    }
}

// ---------------------------------------------------------------------------
// GEMM1 (MFMA): hg = h @ W2; h bf16 rows (256 B), hg -> fp8 rows (128 B).
//   hg8 slot gl (uint2, 8 B) of row n holds channels {16j+gl, j=0..7}.
//   Fragment layouts (HW-verified m89/m91/m120):
//     A[m=lane&15][k=quad*8+j], B[k=quad*8+j][n=lane&15], D col=lane&15,
//     row=quad*4+reg.
// ---------------------------------------------------------------------------
__global__ __launch_bounds__(256) void k_gemm1(
    const u32* __restrict__ hb, const float* __restrict__ W2,
    uint2* __restrict__ hg8)
{
    int lane = threadIdx.x & 63;
    int wv = threadIdx.x >> 6;
    int quad = lane >> 4;
    int l15 = lane & 15;

    // B fragments [kc][n0], once per block (W2 is L2-hot)
    bf16x8 bfrag[4][8];
#pragma unroll
    for (int kc = 0; kc < 4; ++kc) {
#pragma unroll
        for (int n0 = 0; n0 < 8; ++n0) {
            int kbase = kc * 32 + quad * 8;
            int col = n0 * 16 + l15;
            union { bf16x8 v; u32 u[4]; } t;
#pragma unroll
            for (int jj = 0; jj < 4; ++jj) {
                float w0 = W2[(kbase + 2 * jj) * CH + col];
                float w1 = W2[(kbase + 2 * jj + 1) * CH + col];
                t.u[jj] = pack2(w0, w1);
            }
            bfrag[kc][n0] = t.v;
        }
    }

    const int nchunk = (NN + 63) / 64;       // 1563
    for (int ch = blockIdx.x; ch < nchunk; ch += gridDim.x) {
        int m0 = ch * 64 + wv * 16;
        int arow = m0 + l15;
        if (arow >= NN) arow = NN - 1;       // clamp (stores guarded)
        const uint4* ap = (const uint4*)(hb + (size_t)arow * 64);

        bf16x8 afrag[4];
#pragma unroll
        for (int kc = 0; kc < 4; ++kc) {
            union { uint4 q; bf16x8 v; } t;
            t.q = ap[kc * 4 + quad];
            afrag[kc] = t.v;
        }

        f32x4 acc[8];
#pragma unroll
        for (int n0 = 0; n0 < 8; ++n0) acc[n0] = (f32x4){0.f, 0.f, 0.f, 0.f};
#pragma unroll
        for (int n0 = 0; n0 < 8; ++n0)
#pragma unroll
            for (int kc = 0; kc < 4; ++kc)
                acc[n0] = __builtin_amdgcn_mfma_f32_16x16x32_bf16(
                    afrag[kc], bfrag[kc][n0], acc[n0], 0, 0, 0);

#pragma unroll
        for (int r = 0; r < 4; ++r) {
            int row = m0 + quad * 4 + r;
            if (row < NN) {
                int a = pk_fp8<false>(acc[0][r], acc[1][r], 0);
                a = pk_fp8<true>(acc[2][r], acc[3][r], a);
                int b = pk_fp8<false>(acc[4][r], acc[5][r], 0);
                b = pk_fp8<true>(acc[6][r], acc[7][r], b);
                hg8[(size_t)row * 16 + l15] = make_uint2((u32)a, (u32)b);
            }
        }
    }
}

// ---------------------------------------------------------------------------
// k_h2f (wave/node; 4 edge-groups of 16) with the same depth-2 pipeline:
//   one 16B erec load/edge: {src, -, eid, ex}; alpha = ex/den_g[n];
//   out_alpha[eid] = alpha; h2 += alpha * hg8[src] (fp8, chans 16j+gl);
//   out[n,:] = relu(h2+b_gcn)@W3 + b3.  (norm == alpha: deg == 1 identity)
// ---------------------------------------------------------------------------
__global__ __launch_bounds__(256) void k_h2f(
    const u32* __restrict__ rowptr, const uint4* __restrict__ erec,
    const float* __restrict__ den_g, const uint2* __restrict__ hg8,
    const float* __restrict__ bgcn, const float* __restrict__ W3,
    const float* __restrict__ b3,
    float* __restrict__ out_alpha, float* __restrict__ out)
{
    int n = (blockIdx.x << 2) + (threadIdx.x >> 6);
    int lane = threadIdx.x & 63;
    int g = lane >> 4;
    int gl = lane & 15;

    float w30[8], w31[8], bg[8];
#pragma unroll
    for (int j = 0; j < 8; ++j) {
        int c = 16 * j + gl;
        w30[j] = W3[2 * c];
        w31[j] = W3[2 * c + 1];
        bg[j]  = bgcn[c];
    }

    float dn = den_g[n];
    float rden = (dn > 1e-30f) ? 1.f / dn : 0.f;
    u32 p0 = rowptr[n], p1 = rowptr[n + 1];
    u32 last = p1 - 1;
    float acc[8] = {0.f, 0.f, 0.f, 0.f, 0.f, 0.f, 0.f, 0.f};

    u32 p = p0 + g;
    uint4 er0 = erec[p <= last ? p : last];
    uint4 er1 = erec[p + 4 <= last ? p + 4 : last];
    uint2 w0 = hg8[(size_t)er0.x * 16 + gl];

    for (; p < p1; p += 4) {
        uint4 er2 = erec[p + 8 <= last ? p + 8 : last];   // prefetch
        uint2 w1 = hg8[(size_t)er1.x * 16 + gl];          // prefetch
        float a = __uint_as_float(er0.w) * rden;
        if (gl == 0) out_alpha[er0.z] = a;
        f32x2 d0 = unpk_fp8<false>(w0.x), d1 = unpk_fp8<true>(w0.x);
        f32x2 d2 = unpk_fp8<false>(w0.y), d3 = unpk_fp8<true>(w0.y);
        acc[0] += a * d0.x; acc[1] += a * d0.y;
        acc[2] += a * d1.x; acc[3] += a * d1.y;
        acc[4] += a * d2.x; acc[5] += a * d2.y;
        acc[6] += a * d3.x; acc[7] += a * d3.y;
        er0 = er1; er1 = er2; w0 = w1;
    }
#pragma unroll
    for (int j = 0; j < 8; ++j) {
        acc[j] += __shfl_xor(acc[j], 16, 64);
        acc[j] += __shfl_xor(acc[j], 32, 64);
    }
    float o0 = 0.f, o1 = 0.f;
#pragma unroll
    for (int j = 0; j < 8; ++j) {
        float v = acc[j] + bg[j];
        v = v > 0.f ? v : 0.f;
        o0 += v * w30[j];
        o1 += v * w31[j];
    }
    o0 += __shfl_xor(o0, 1, 64); o1 += __shfl_xor(o1, 1, 64);
    o0 += __shfl_xor(o0, 2, 64); o1 += __shfl_xor(o1, 2, 64);
    o0 += __shfl_xor(o0, 4, 64); o1 += __shfl_xor(o1, 4, 64);
    o0 += __shfl_xor(o0, 8, 64); o1 += __shfl_xor(o1, 8, 64);
    if (lane == 0) {
        out[n * 2]     = o0 + b3[0];
        out[n * 2 + 1] = o1 + b3[1];
    }
}

// ---------------------------------------------------------------------------
extern "C" void kernel_launch(void* const* d_in, const int* in_sizes, int n_in,
                              void* d_out, int out_size, void* d_ws, size_t ws_size,
                              hipStream_t stream)
{
    const float* x    = (const float*)d_in[0];
    const int*   ei   = (const int*)d_in[1];
    const float* ew   = (const float*)d_in[2];
    const float* Wl   = (const float*)d_in[3];
    const float* bl   = (const float*)d_in[4];
    const float* Wr   = (const float*)d_in[5];
    const float* br   = (const float*)d_in[6];
    const float* We   = (const float*)d_in[7];
    const float* att  = (const float*)d_in[8];
    const float* bgat = (const float*)d_in[9];
    const float* W2   = (const float*)d_in[10];
    const float* bgcn = (const float*)d_in[11];
    const float* W3   = (const float*)d_in[12];
    const float* b3   = (const float*)d_in[13];

    float* out       = (float*)d_out;          // chunk0: out [N,2] f32
    float* out_idx   = out + 200000;           // chunk1: stack([src,dst]) [2,ET]
    float* out_alpha = out + 200000 + 2 * ET;  // chunk2: alpha [ET,1]

    // workspace (~66.5 MB):
    // xl8 u32[NN*32] (fp8 xl; later hg8 fp8)  | xrh uint2[NN*32] (bf16 xr -> h)
    // | erec uint4[ET] | cnt u32[NN] (later den_g f32) | rowptr[NN+1] | bsum[512]
    u32*   xl8    = (u32*)d_ws;
    uint2* xrh    = (uint2*)(xl8 + (size_t)NN * 32);
    uint4* erec   = (uint4*)(xrh + (size_t)NN * 32);
    u32*   cnt    = (u32*)(erec + ET);
    float* den    = (float*)cnt;               // aliased after scatter
    u32*   rowptr = cnt + NN;
    u32*   bsum   = rowptr + NN + 1;

    const int EB = (ET + 255) / 256;
    const int SB = (NN + 255) / 256;           // 391

    // --- CSR build (+ out_idx) ---
    hipMemsetAsync(cnt, 0, NN * sizeof(u32), stream);
    k_deg<<<EB, 256, 0, stream>>>(ei, cnt);
    k_scanA<<<SB, 256, 0, stream>>>(cnt, bsum);
    k_scanB<<<1, 512, 0, stream>>>(bsum, SB);
    k_scanC<<<SB, 256, 0, stream>>>(cnt, bsum, rowptr);   // also zeroes cnt
    k_scatter<<<EB, 256, 0, stream>>>(ei, ew, rowptr, cnt, erec, out_idx);

    // --- projections + fused attention/aggregation ---
    k_pre<<<(NN * 32) / 256, 256, 0, stream>>>(x, Wl, bl, Wr, br, xl8, xrh);
    k_fused<<<NN / 4, 256, 0, stream>>>(rowptr, erec, xl8, We, att, bgat,
                                        (uint4*)xrh, den);

    // --- GCN (MFMA, fp8 out) + fused h2+MLP ---
    k_gemm1<<<512, 256, 0, stream>>>((const u32*)xrh, W2, (uint2*)xl8);
    k_h2f<<<NN / 4, 256, 0, stream>>>(rowptr, erec, den, (const uint2*)xl8,
                                      bgcn, W3, b3, out_alpha, out);
}